// Round 2
// baseline (176.631 us; speedup 1.0000x reference)
//
#include <hip/hip_runtime.h>
#include <math.h>

#define S_LEN 2048
#define B_TOT 4096
#define CHUNK 16                 // steps per lane = S_LEN / 128 (2 waves per batch)
constexpr float DT       = 1.0f / 200.0f;
constexpr float HALF_DT2 = DT * DT * 0.5f;

// One preintegration step applied to running segment state (R,V,P).
//   R <- R * Rod(w*dt);  t = R*a;  V += t*dt;  P += V*dt + t*half_dt2
__device__ __forceinline__ void istep(
    float& R00, float& R01, float& R02,
    float& R10, float& R11, float& R12,
    float& R20, float& R21, float& R22,
    float& Vx, float& Vy, float& Vz,
    float& Px, float& Py, float& Pz,
    float wx, float wy, float wz, float ax, float ay, float az)
{
    const float ux = wx * DT, uy = wy * DT, uz = wz * DT;
    const float t2 = ux * ux + uy * uy + uz * uz;          // theta^2 (tiny)
    // a = sin(t)/t, b = (1-cos(t))/t^2 via Taylor in t^2 (t <= ~0.04)
    const float Ac = 1.0f + t2 * (-1.0f / 6.0f  + t2 * (1.0f / 120.0f));
    const float Bc = 0.5f + t2 * (-1.0f / 24.0f + t2 * (1.0f / 720.0f));

    // K = I + Ac*skew(u) + Bc*(u u^T - t2*I)
    const float K00 = 1.0f + Bc * (ux * ux - t2);
    const float K11 = 1.0f + Bc * (uy * uy - t2);
    const float K22 = 1.0f + Bc * (uz * uz - t2);
    const float bxy = Bc * ux * uy, bxz = Bc * ux * uz, byz = Bc * uy * uz;
    const float aux = Ac * ux, auy = Ac * uy, auz = Ac * uz;
    const float K01 = bxy - auz, K10 = bxy + auz;
    const float K02 = bxz + auy, K20 = bxz - auy;
    const float K12 = byz - aux, K21 = byz + aux;

    // R = R * K
    float r0, r1, r2;
    r0 = R00 * K00 + R01 * K10 + R02 * K20;
    r1 = R00 * K01 + R01 * K11 + R02 * K21;
    r2 = R00 * K02 + R01 * K12 + R02 * K22;
    R00 = r0; R01 = r1; R02 = r2;
    r0 = R10 * K00 + R11 * K10 + R12 * K20;
    r1 = R10 * K01 + R11 * K11 + R12 * K21;
    r2 = R10 * K02 + R11 * K12 + R12 * K22;
    R10 = r0; R11 = r1; R12 = r2;
    r0 = R20 * K00 + R21 * K10 + R22 * K20;
    r1 = R20 * K01 + R21 * K11 + R22 * K21;
    r2 = R20 * K02 + R21 * K12 + R22 * K22;
    R20 = r0; R21 = r1; R22 = r2;

    // t = R * a  (uses updated R, matching reference ordering)
    const float tx = R00 * ax + R01 * ay + R02 * az;
    const float ty = R10 * ax + R11 * ay + R12 * az;
    const float tz = R20 * ax + R21 * ay + R22 * az;
    Vx += tx * DT; Vy += ty * DT; Vz += tz * DT;
    Px += Vx * DT + tx * HALF_DT2;
    Py += Vy * DT + ty * HALF_DT2;
    Pz += Vz * DT + tz * HALF_DT2;
}

// block = 256 threads = 4 waves = 2 batches (2 waves per batch).
// __launch_bounds__(256, 8): force VGPR <= 64 so 8 waves/SIMD are resident.
__global__ __launch_bounds__(256, 8)
void preint_kernel(const float* __restrict__ in, float* __restrict__ out)
{
    const int slot = threadIdx.x >> 7;             // batch within block (0..1)
    const int b    = blockIdx.x * 2 + slot;
    const int tid  = threadIdx.x & 127;            // thread within batch
    const int lane = threadIdx.x & 63;
    const int half = (threadIdx.x >> 6) & 1;       // which wave of the batch

    const float4* p4 =
        reinterpret_cast<const float4*>(in + ((size_t)b * S_LEN + (size_t)tid * CHUNK) * 6);

    // per-lane segment state, starting from (I, 0, 0)
    float R00 = 1.f, R01 = 0.f, R02 = 0.f;
    float R10 = 0.f, R11 = 1.f, R12 = 0.f;
    float R20 = 0.f, R21 = 0.f, R22 = 1.f;
    float Vx = 0.f, Vy = 0.f, Vz = 0.f;
    float Px = 0.f, Py = 0.f, Pz = 0.f;

    float4 q0 = p4[0], q1 = p4[1], q2 = p4[2];
    for (int it = 0; it < CHUNK / 2; ++it) {
        const int ni = (it < CHUNK / 2 - 1) ? 3 * (it + 1) : 0;  // prefetch (wrap on tail)
        const float4 n0 = p4[ni], n1 = p4[ni + 1], n2 = p4[ni + 2];
        // step 0: w=(q0.x,q0.y,q0.z) a=(q0.w,q1.x,q1.y)
        istep(R00,R01,R02,R10,R11,R12,R20,R21,R22,Vx,Vy,Vz,Px,Py,Pz,
              q0.x, q0.y, q0.z, q0.w, q1.x, q1.y);
        // step 1: w=(q1.z,q1.w,q2.x) a=(q2.y,q2.z,q2.w)
        istep(R00,R01,R02,R10,R11,R12,R20,R21,R22,Vx,Vy,Vz,Px,Py,Pz,
              q1.z, q1.w, q2.x, q2.y, q2.z, q2.w);
        q0 = n0; q1 = n1; q2 = n2;
    }

    // ordered tree reduction across the wave: lane i holds chunks [i, i+o)
    #pragma unroll
    for (int o = 1; o < 64; o <<= 1) {
        const float Tb = (float)(o * CHUNK) * DT;   // duration of B's segment
        const float S00 = __shfl_down(R00, o, 64), S01 = __shfl_down(R01, o, 64), S02 = __shfl_down(R02, o, 64);
        const float S10 = __shfl_down(R10, o, 64), S11 = __shfl_down(R11, o, 64), S12 = __shfl_down(R12, o, 64);
        const float S20 = __shfl_down(R20, o, 64), S21 = __shfl_down(R21, o, 64), S22 = __shfl_down(R22, o, 64);
        const float Wx  = __shfl_down(Vx, o, 64),  Wy  = __shfl_down(Vy, o, 64),  Wz  = __shfl_down(Vz, o, 64);
        const float Qx  = __shfl_down(Px, o, 64),  Qy  = __shfl_down(Py, o, 64),  Qz  = __shfl_down(Pz, o, 64);

        // P = P_A + V_A*T_B + R_A * P_B
        const float nPx = Px + Vx * Tb + R00 * Qx + R01 * Qy + R02 * Qz;
        const float nPy = Py + Vy * Tb + R10 * Qx + R11 * Qy + R12 * Qz;
        const float nPz = Pz + Vz * Tb + R20 * Qx + R21 * Qy + R22 * Qz;
        // V = V_A + R_A * V_B
        const float nVx = Vx + R00 * Wx + R01 * Wy + R02 * Wz;
        const float nVy = Vy + R10 * Wx + R11 * Wy + R12 * Wz;
        const float nVz = Vz + R20 * Wx + R21 * Wy + R22 * Wz;
        // R = R_A * R_B
        float r0, r1, r2;
        r0 = R00 * S00 + R01 * S10 + R02 * S20;
        r1 = R00 * S01 + R01 * S11 + R02 * S21;
        r2 = R00 * S02 + R01 * S12 + R02 * S22;
        R00 = r0; R01 = r1; R02 = r2;
        r0 = R10 * S00 + R11 * S10 + R12 * S20;
        r1 = R10 * S01 + R11 * S11 + R12 * S21;
        r2 = R10 * S02 + R11 * S12 + R12 * S22;
        R10 = r0; R11 = r1; R12 = r2;
        r0 = R20 * S00 + R21 * S10 + R22 * S20;
        r1 = R20 * S01 + R21 * S11 + R22 * S21;
        r2 = R20 * S02 + R21 * S12 + R22 * S22;
        R20 = r0; R21 = r1; R22 = r2;

        Px = nPx; Py = nPy; Pz = nPz;
        Vx = nVx; Vy = nVy; Vz = nVz;
    }

    // cross-wave combine: wave 'half' of each batch parks its state in LDS
    __shared__ float st[2][2][16];
    if (lane == 0) {
        float* s = st[slot][half];
        s[0]=R00; s[1]=R01; s[2]=R02; s[3]=R10; s[4]=R11; s[5]=R12;
        s[6]=R20; s[7]=R21; s[8]=R22; s[9]=Vx; s[10]=Vy; s[11]=Vz;
        s[12]=Px; s[13]=Py; s[14]=Pz;
    }
    __syncthreads();

    if (tid == 0) {
        // A = this thread's registers (steps 0..1023), B = other wave's state
        const float* s = st[slot][1];
        const float S00=s[0],S01=s[1],S02=s[2],S10=s[3],S11=s[4],S12=s[5];
        const float S20=s[6],S21=s[7],S22=s[8],Wx=s[9],Wy=s[10],Wz=s[11];
        const float Qx=s[12],Qy=s[13],Qz=s[14];
        const float Tb = (float)(64 * CHUNK) * DT;

        const float nPx = Px + Vx * Tb + R00 * Qx + R01 * Qy + R02 * Qz;
        const float nPy = Py + Vy * Tb + R10 * Qx + R11 * Qy + R12 * Qz;
        const float nPz = Pz + Vz * Tb + R20 * Qx + R21 * Qy + R22 * Qz;
        float r0, r1, r2;
        r0 = R00 * S00 + R01 * S10 + R02 * S20;
        r1 = R00 * S01 + R01 * S11 + R02 * S21;
        r2 = R00 * S02 + R01 * S12 + R02 * S22;
        const float F00 = r0, F01 = r1, F02 = r2;
        r0 = R10 * S00 + R11 * S10 + R12 * S20;
        r1 = R10 * S01 + R11 * S11 + R12 * S21;
        r2 = R10 * S02 + R11 * S12 + R12 * S22;
        const float F10 = r0, F11 = r1, F12 = r2;
        r0 = R20 * S00 + R21 * S10 + R22 * S20;
        r1 = R20 * S01 + R21 * S11 + R22 * S21;
        r2 = R20 * S02 + R21 * S12 + R22 * S22;
        const float F20 = r0, F21 = r1, F22 = r2;

        // rotation matrix -> axis-angle -> quaternion (mirrors reference)
        const float tr = F00 + F11 + F22;
        float c = (tr - 1.0f) * 0.5f;
        c = fminf(fmaxf(c, -1.0f + 1e-7f), 1.0f - 1e-7f);
        const float angle = acosf(c);
        const float sden = fmaxf(2.0f * sinf(angle), 1e-12f);
        const float axx = (F21 - F12) / sden;
        const float ayy = (F02 - F20) / sden;
        const float azz = (F10 - F01) / sden;
        const float halfang = angle * 0.5f;
        const float sh = sinf(halfang), ch = cosf(halfang);
        float* o = out + (size_t)b * 7;
        o[0] = nPx; o[1] = nPy; o[2] = nPz;
        o[3] = ch;
        o[4] = axx * sh; o[5] = ayy * sh; o[6] = azz * sh;
    }
}

extern "C" void kernel_launch(void* const* d_in, const int* in_sizes, int n_in,
                              void* d_out, int out_size, void* d_ws, size_t ws_size,
                              hipStream_t stream)
{
    const float* in = (const float*)d_in[0];
    float* out = (float*)d_out;
    const int threads = 256;
    const int blocks = B_TOT / 2;   // 2048 blocks, 2 batches per block
    preint_kernel<<<blocks, threads, 0, stream>>>(in, out);
}

// Round 3
// 57.010 us; speedup vs baseline: 3.0982x; 3.0982x over previous
//
#include <hip/hip_runtime.h>
#include <math.h>

#define S_LEN 2048
#define B_TOT 4096
#define CHUNK 32                  // steps per lane (1 wave per batch)
#define PH_STEPS 4                // steps per phase
#define N_PH (CHUNK / PH_STEPS)   // 8 phases
constexpr float DT       = 1.0f / 200.0f;
constexpr float HALF_DT2 = DT * DT * 0.5f;

// One preintegration step applied to running segment state (R,V,P).
__device__ __forceinline__ void istep(
    float& R00, float& R01, float& R02,
    float& R10, float& R11, float& R12,
    float& R20, float& R21, float& R22,
    float& Vx, float& Vy, float& Vz,
    float& Px, float& Py, float& Pz,
    float wx, float wy, float wz, float ax, float ay, float az)
{
    const float ux = wx * DT, uy = wy * DT, uz = wz * DT;
    const float t2 = ux * ux + uy * uy + uz * uz;          // theta^2 (tiny)
    const float Ac = 1.0f + t2 * (-1.0f / 6.0f  + t2 * (1.0f / 120.0f));
    const float Bc = 0.5f + t2 * (-1.0f / 24.0f + t2 * (1.0f / 720.0f));

    const float K00 = 1.0f + Bc * (ux * ux - t2);
    const float K11 = 1.0f + Bc * (uy * uy - t2);
    const float K22 = 1.0f + Bc * (uz * uz - t2);
    const float bxy = Bc * ux * uy, bxz = Bc * ux * uz, byz = Bc * uy * uz;
    const float aux = Ac * ux, auy = Ac * uy, auz = Ac * uz;
    const float K01 = bxy - auz, K10 = bxy + auz;
    const float K02 = bxz + auy, K20 = bxz - auy;
    const float K12 = byz - aux, K21 = byz + aux;

    float r0, r1, r2;
    r0 = R00 * K00 + R01 * K10 + R02 * K20;
    r1 = R00 * K01 + R01 * K11 + R02 * K21;
    r2 = R00 * K02 + R01 * K12 + R02 * K22;
    R00 = r0; R01 = r1; R02 = r2;
    r0 = R10 * K00 + R11 * K10 + R12 * K20;
    r1 = R10 * K01 + R11 * K11 + R12 * K21;
    r2 = R10 * K02 + R11 * K12 + R12 * K22;
    R10 = r0; R11 = r1; R12 = r2;
    r0 = R20 * K00 + R21 * K10 + R22 * K20;
    r1 = R20 * K01 + R21 * K11 + R22 * K21;
    r2 = R20 * K02 + R21 * K12 + R22 * K22;
    R20 = r0; R21 = r1; R22 = r2;

    const float tx = R00 * ax + R01 * ay + R02 * az;
    const float ty = R10 * ax + R11 * ay + R12 * az;
    const float tz = R20 * ax + R21 * ay + R22 * az;
    Vx += tx * DT; Vy += ty * DT; Vz += tz * DT;
    Px += Vx * DT + tx * HALF_DT2;
    Py += Vy * DT + ty * HALF_DT2;
    Pz += Vz * DT + tz * HALF_DT2;
}

// block = 256 = 4 waves = 4 batches. __launch_bounds__(256,4): VGPR cap 128
// (4 waves/SIMD is all the 4096-wave grid can use; ~110 live regs, no spill).
__global__ __launch_bounds__(256, 4)
void preint_kernel(const float* __restrict__ in, float* __restrict__ out)
{
    const int w    = threadIdx.x >> 6;             // wave in block (0..3)
    const int b    = blockIdx.x * 4 + w;           // batch = wave
    const int lane = threadIdx.x & 63;

    // LDS: per wave, 6 "idx" slabs of 64 pieces (+1 pad entry -> 1040B stride).
    // lds[w][idx][piece] holds float4 #idx of lane 'piece's current phase.
    // write banks = 4*(idx+piece)+d (uniform); read (idx fixed) = 4*piece+d.
    __shared__ float4 lds[4][6][65];

    // phase gather mapping: flat id = m*64 + lane enumerates the 384 float4s
    // of a phase in piece-major order; piece = id/6, idx = id%6.
    // global float4 index = piece*48 + p*6 + idx  (lane chunk = 48 float4s).
    int ginv[6], pc[6], ix[6];
    #pragma unroll
    for (int m = 0; m < 6; ++m) {
        const int id = m * 64 + lane;
        pc[m] = id / 6;
        ix[m] = id % 6;
        ginv[m] = pc[m] * 48 + ix[m];
    }

    const float4* g4 = reinterpret_cast<const float4*>(in) + (size_t)b * (S_LEN * 6 / 4);

    // prologue: stage phase 0
    {
        float4 n[6];
        #pragma unroll
        for (int m = 0; m < 6; ++m) n[m] = g4[ginv[m]];
        #pragma unroll
        for (int m = 0; m < 6; ++m) lds[w][ix[m]][pc[m]] = n[m];
    }

    float R00 = 1.f, R01 = 0.f, R02 = 0.f;
    float R10 = 0.f, R11 = 1.f, R12 = 0.f;
    float R20 = 0.f, R21 = 0.f, R22 = 1.f;
    float Vx = 0.f, Vy = 0.f, Vz = 0.f;
    float Px = 0.f, Py = 0.f, Pz = 0.f;

    #pragma unroll 1
    for (int p = 0; p < N_PH; ++p) {
        // issue next phase's coalesced loads early (latency hides under compute)
        float4 n0, n1, n2, n3, n4, n5;
        if (p < N_PH - 1) {
            const int o = (p + 1) * 6;
            n0 = g4[ginv[0] + o]; n1 = g4[ginv[1] + o]; n2 = g4[ginv[2] + o];
            n3 = g4[ginv[3] + o]; n4 = g4[ginv[4] + o]; n5 = g4[ginv[5] + o];
        }

        // read this phase (lane reads its own piece across the 6 slabs)
        const float4 q0 = lds[w][0][lane], q1 = lds[w][1][lane], q2 = lds[w][2][lane];
        const float4 q3 = lds[w][3][lane], q4 = lds[w][4][lane], q5 = lds[w][5][lane];

        istep(R00,R01,R02,R10,R11,R12,R20,R21,R22,Vx,Vy,Vz,Px,Py,Pz,
              q0.x, q0.y, q0.z, q0.w, q1.x, q1.y);
        istep(R00,R01,R02,R10,R11,R12,R20,R21,R22,Vx,Vy,Vz,Px,Py,Pz,
              q1.z, q1.w, q2.x, q2.y, q2.z, q2.w);
        istep(R00,R01,R02,R10,R11,R12,R20,R21,R22,Vx,Vy,Vz,Px,Py,Pz,
              q3.x, q3.y, q3.z, q3.w, q4.x, q4.y);
        istep(R00,R01,R02,R10,R11,R12,R20,R21,R22,Vx,Vy,Vz,Px,Py,Pz,
              q4.z, q4.w, q5.x, q5.y, q5.z, q5.w);

        // write next phase into LDS (reads above already consumed; same-wave
        // DS ops to identical addresses keep program order — no barrier)
        if (p < N_PH - 1) {
            lds[w][ix[0]][pc[0]] = n0; lds[w][ix[1]][pc[1]] = n1;
            lds[w][ix[2]][pc[2]] = n2; lds[w][ix[3]][pc[3]] = n3;
            lds[w][ix[4]][pc[4]] = n4; lds[w][ix[5]][pc[5]] = n5;
        }
    }

    // ordered tree reduction across the wave: lane i holds chunks [i, i+o)
    #pragma unroll
    for (int o = 1; o < 64; o <<= 1) {
        const float Tb = (float)(o * CHUNK) * DT;
        const float S00 = __shfl_down(R00, o, 64), S01 = __shfl_down(R01, o, 64), S02 = __shfl_down(R02, o, 64);
        const float S10 = __shfl_down(R10, o, 64), S11 = __shfl_down(R11, o, 64), S12 = __shfl_down(R12, o, 64);
        const float S20 = __shfl_down(R20, o, 64), S21 = __shfl_down(R21, o, 64), S22 = __shfl_down(R22, o, 64);
        const float Wx  = __shfl_down(Vx, o, 64),  Wy  = __shfl_down(Vy, o, 64),  Wz  = __shfl_down(Vz, o, 64);
        const float Qx  = __shfl_down(Px, o, 64),  Qy  = __shfl_down(Py, o, 64),  Qz  = __shfl_down(Pz, o, 64);

        const float nPx = Px + Vx * Tb + R00 * Qx + R01 * Qy + R02 * Qz;
        const float nPy = Py + Vy * Tb + R10 * Qx + R11 * Qy + R12 * Qz;
        const float nPz = Pz + Vz * Tb + R20 * Qx + R21 * Qy + R22 * Qz;
        const float nVx = Vx + R00 * Wx + R01 * Wy + R02 * Wz;
        const float nVy = Vy + R10 * Wx + R11 * Wy + R12 * Wz;
        const float nVz = Vz + R20 * Wx + R21 * Wy + R22 * Wz;
        float r0, r1, r2;
        r0 = R00 * S00 + R01 * S10 + R02 * S20;
        r1 = R00 * S01 + R01 * S11 + R02 * S21;
        r2 = R00 * S02 + R01 * S12 + R02 * S22;
        R00 = r0; R01 = r1; R02 = r2;
        r0 = R10 * S00 + R11 * S10 + R12 * S20;
        r1 = R10 * S01 + R11 * S11 + R12 * S21;
        r2 = R10 * S02 + R11 * S12 + R12 * S22;
        R10 = r0; R11 = r1; R12 = r2;
        r0 = R20 * S00 + R21 * S10 + R22 * S20;
        r1 = R20 * S01 + R21 * S11 + R22 * S21;
        r2 = R20 * S02 + R21 * S12 + R22 * S22;
        R20 = r0; R21 = r1; R22 = r2;

        Px = nPx; Py = nPy; Pz = nPz;
        Vx = nVx; Vy = nVy; Vz = nVz;
    }

    if (lane == 0) {
        const float tr = R00 + R11 + R22;
        float c = (tr - 1.0f) * 0.5f;
        c = fminf(fmaxf(c, -1.0f + 1e-7f), 1.0f - 1e-7f);
        const float angle = acosf(c);
        const float s = fmaxf(2.0f * sinf(angle), 1e-12f);
        const float axx = (R21 - R12) / s;
        const float ayy = (R02 - R20) / s;
        const float azz = (R10 - R01) / s;
        const float half = angle * 0.5f;
        const float sh = sinf(half), ch = cosf(half);
        float* o = out + (size_t)b * 7;
        o[0] = Px; o[1] = Py; o[2] = Pz;
        o[3] = ch;
        o[4] = axx * sh; o[5] = ayy * sh; o[6] = azz * sh;
    }
}

extern "C" void kernel_launch(void* const* d_in, const int* in_sizes, int n_in,
                              void* d_out, int out_size, void* d_ws, size_t ws_size,
                              hipStream_t stream)
{
    const float* in = (const float*)d_in[0];
    float* out = (float*)d_out;
    const int threads = 256;
    const int blocks = B_TOT / 4;   // 1024 blocks, 4 batches (waves) per block
    preint_kernel<<<blocks, threads, 0, stream>>>(in, out);
}